// Round 1
// baseline (94.887 us; speedup 1.0000x reference)
//
#include <hip/hip_runtime.h>
#include <math.h>

// Fully-fused C3DNet: one workgroup per sample (batch=10), all intermediate
// state in LDS, __syncthreads() between stages. Latency-bound problem
// (~3.1M MACs total), so minimize kernel count and keep the chain on-chip.

__device__ __forceinline__ float sigmoidf(float x) {
    return 1.0f / (1.0f + expf(-x));
}

__global__ __launch_bounds__(256) void c3dnet_fused(
    const float* __restrict__ x,    // (10, 1, 52, 7, 24) per-sample 8736 floats
    const float* __restrict__ w1,   // (6,2,2) = 24
    const float* __restrict__ b1,   // (1)
    const float* __restrict__ w2,   // (4,1,2) = 8
    const float* __restrict__ b2,   // (1)
    const float* __restrict__ w4,   // (80,27)
    const float* __restrict__ b4,   // (80)
    const float* __restrict__ w5,   // (200,80)
    const float* __restrict__ b5,   // (200)
    const float* __restrict__ w6,   // (676,200)
    const float* __restrict__ b6,   // (676)
    float* __restrict__ out)        // (10, 2184)
{
    const int b   = blockIdx.x;    // sample index, 0..9
    const int tid = threadIdx.x;   // 0..255

    // ---- LDS state (≈47 KB) ----
    __shared__ __align__(16) float xs_sh[8736];   // input sample / "weeks" (52,168)
    __shared__ __align__(16) float h1_sh[1728];   // conv1 out (24,6,12)
    __shared__ __align__(16) float h2_sh[216];    // conv2 out (6,6,6)
    __shared__ __align__(16) float pool_sh[27];   // avgpool out (3,3,3)
    __shared__ __align__(16) float f1_sh[80];
    __shared__ __align__(16) float f2_sh[200];
    __shared__ __align__(16) float f3_sh[676];
    __shared__ float w1_sh[24];
    __shared__ float w2_sh[8];
    __shared__ float b1_sh, b2_sh;

    // ---- Stage 0: load sample + tiny conv weights into LDS ----
    {
        const float4* src = (const float4*)(x + (size_t)b * 8736);
        float4* dst = (float4*)xs_sh;
        for (int i = tid; i < 2184; i += 256) dst[i] = src[i];   // 8736 floats
        if (tid < 24) w1_sh[tid] = w1[tid];
        if (tid < 8)  w2_sh[tid] = w2[tid];
        if (tid == 0) { b1_sh = b1[0]; b2_sh = b2[0]; }
    }
    __syncthreads();

    // ---- Stage 1: conv1 (6,2,2) stride (2,1,2), sigmoid -> (24,6,12) ----
    for (int o = tid; o < 1728; o += 256) {
        const int d = o / 72;
        const int r = o % 72;
        const int h = r / 12;
        const int w = r % 12;
        const float* src = &xs_sh[(2 * d) * 168 + h * 24 + 2 * w];
        float acc = b1_sh;
        #pragma unroll
        for (int kd = 0; kd < 6; ++kd)
            #pragma unroll
            for (int kh = 0; kh < 2; ++kh)
                #pragma unroll
                for (int kw = 0; kw < 2; ++kw)
                    acc += src[kd * 168 + kh * 24 + kw] * w1_sh[kd * 4 + kh * 2 + kw];
        h1_sh[o] = sigmoidf(acc);
    }
    __syncthreads();

    // ---- Stage 2: conv2 (4,1,2) stride (4,1,2), sigmoid -> (6,6,6) ----
    if (tid < 216) {
        const int d = tid / 36;
        const int r = tid % 36;
        const int h = r / 6;
        const int w = r % 6;
        float acc = b2_sh;
        #pragma unroll
        for (int kd = 0; kd < 4; ++kd)
            #pragma unroll
            for (int kw = 0; kw < 2; ++kw)
                acc += h1_sh[(4 * d + kd) * 72 + h * 12 + (2 * w + kw)] * w2_sh[kd * 2 + kw];
        h2_sh[tid] = sigmoidf(acc);
    }
    __syncthreads();

    // ---- Stage 3: avgpool k=2 -> (3,3,3) = 27 ----
    if (tid < 27) {
        const int d = tid / 9;
        const int r = tid % 9;
        const int h = r / 3;
        const int w = r % 3;
        float s = 0.f;
        #pragma unroll
        for (int dd = 0; dd < 2; ++dd)
            #pragma unroll
            for (int hh = 0; hh < 2; ++hh)
                #pragma unroll
                for (int ww = 0; ww < 2; ++ww)
                    s += h2_sh[(2 * d + dd) * 36 + (2 * h + hh) * 6 + (2 * w + ww)];
        pool_sh[tid] = s * 0.125f;
    }
    __syncthreads();

    // ---- Stage 4: fc1 27 -> 80, sigmoid ----
    if (tid < 80) {
        const float* wr = w4 + tid * 27;
        float acc = b4[tid];
        #pragma unroll
        for (int i = 0; i < 27; ++i) acc += pool_sh[i] * wr[i];
        f1_sh[tid] = sigmoidf(acc);
    }
    __syncthreads();

    // ---- Stage 5: fc2 80 -> 200, sigmoid (float4 rows, stride 80*4B = 16B-aligned) ----
    if (tid < 200) {
        const float4* wr = (const float4*)(w5 + tid * 80);
        const float4* fv = (const float4*)f1_sh;
        float acc = b5[tid];
        #pragma unroll
        for (int i = 0; i < 20; ++i) {
            float4 a = wr[i], c = fv[i];
            acc += a.x * c.x + a.y * c.y + a.z * c.z + a.w * c.w;
        }
        f2_sh[tid] = sigmoidf(acc);
    }
    __syncthreads();

    // ---- Stage 6: fc3 200 -> 676, sigmoid (row stride 200*4B = 16B-aligned) ----
    for (int o = tid; o < 676; o += 256) {
        const float4* wr = (const float4*)(w6 + o * 200);
        const float4* fv = (const float4*)f2_sh;
        float acc = b6[o];
        #pragma unroll 10
        for (int i = 0; i < 50; ++i) {
            float4 a = wr[i], c = fv[i];
            acc += a.x * c.x + a.y * c.y + a.z * c.z + a.w * c.w;
        }
        f3_sh[o] = sigmoidf(acc);
    }
    __syncthreads();

    // ---- Stage 7: einsum('is,sw->iw'): out[b, i*168+w] = sum_s f3[i*52+s]*weeks[s,w] ----
    // weeks[s,w] == xs_sh[s*168 + w]
    float* ob = out + (size_t)b * 2184;
    for (int o = tid; o < 2184; o += 256) {
        const int i = o / 168;
        const int w = o % 168;
        const float* fr = &f3_sh[i * 52];
        float acc = 0.f;
        #pragma unroll 13
        for (int s = 0; s < 52; ++s)
            acc += fr[s] * xs_sh[s * 168 + w];
        ob[o] = acc;
    }
}

extern "C" void kernel_launch(void* const* d_in, const int* in_sizes, int n_in,
                              void* d_out, int out_size, void* d_ws, size_t ws_size,
                              hipStream_t stream) {
    const float* x  = (const float*)d_in[0];
    const float* w1 = (const float*)d_in[1];
    const float* b1 = (const float*)d_in[2];
    const float* w2 = (const float*)d_in[3];
    const float* b2 = (const float*)d_in[4];
    const float* w4 = (const float*)d_in[5];
    const float* b4 = (const float*)d_in[6];
    const float* w5 = (const float*)d_in[7];
    const float* b5 = (const float*)d_in[8];
    const float* w6 = (const float*)d_in[9];
    const float* b6 = (const float*)d_in[10];
    float* out = (float*)d_out;

    c3dnet_fused<<<10, 256, 0, stream>>>(x, w1, b1, w2, b2, w4, b4,
                                         w5, b5, w6, b6, out);
}

// Round 2
// 83.092 us; speedup vs baseline: 1.1420x; 1.1420x over previous
//
#include <hip/hip_runtime.h>
#include <math.h>

// Fully-fused C3DNet, 13 blocks per sample (grid 13x10).
// Block (i0, b): computes stages conv1..fc2 redundantly (cheap, parallel
// across CUs), then ONLY rows [i0*52, i0*52+52) of fc3 and ONLY output row
// i0 of the final einsum. This 13-way split cuts the two dominant costs
// (fc3 global traffic per block, stage-7 LDS traffic per block) by 13x.
// Latency-bound problem: single kernel, whole chain in LDS.

__device__ __forceinline__ float sigmoidf(float x) {
    return 1.0f / (1.0f + __expf(-x));
}

__global__ __launch_bounds__(256) void c3dnet_fused(
    const float* __restrict__ x,    // (10, 1, 52, 7, 24) per-sample 8736 floats
    const float* __restrict__ w1,   // (6,2,2) = 24
    const float* __restrict__ b1,   // (1)
    const float* __restrict__ w2,   // (4,1,2) = 8
    const float* __restrict__ b2,   // (1)
    const float* __restrict__ w4,   // (80,27)
    const float* __restrict__ b4,   // (80)
    const float* __restrict__ w5,   // (200,80)
    const float* __restrict__ b5,   // (200)
    const float* __restrict__ w6,   // (676,200)
    const float* __restrict__ b6,   // (676)
    float* __restrict__ out)        // (10, 2184)
{
    const int i0  = blockIdx.x;    // output row 0..12
    const int b   = blockIdx.y;    // sample 0..9
    const int tid = threadIdx.x;   // 0..255

    // ---- LDS (~44 KB) ----
    __shared__ __align__(16) float xs_sh[8736];   // sample / weeks (52,168)
    __shared__ __align__(16) float h1_sh[1728];   // conv1 out (24,6,12)
    __shared__ __align__(16) float h2_sh[216];    // conv2 out (6,6,6)
    __shared__ __align__(16) float pool_sh[27];
    __shared__ __align__(16) float f1_sh[80];
    __shared__ __align__(16) float f2_sh[200];
    __shared__ __align__(16) float f3_sh[52];     // only this block's 52 values

    // ---- Stage 0: sample -> LDS (float4) ----
    {
        const float4* src = (const float4*)(x + (size_t)b * 8736);
        float4* dst = (float4*)xs_sh;
        for (int i = tid; i < 2184; i += 256) dst[i] = src[i];
    }
    __syncthreads();

    // ---- Stage 1: conv1 (6,2,2)/s(2,1,2) + sigmoid -> (24,6,12) ----
    // One float4 LDS read covers kw={0,1} for TWO adjacent w-outputs
    // (stride 2, so outputs 2j,2j+1 read elements 4j..4j+3). 864 pair-tasks.
    {
        const float4* xs4 = (const float4*)xs_sh;
        for (int t = tid; t < 864; t += 256) {
            const int d = t / 36;
            const int r = t % 36;
            const int h = r / 6;
            const int j = r % 6;          // w-pair: outputs 2j, 2j+1
            const int base4 = 84 * d + 6 * h + j;   // float4 index of xs[336d+24h+4j]
            float acc0 = b1[0], acc1 = b1[0];
            #pragma unroll
            for (int kd = 0; kd < 6; ++kd)
                #pragma unroll
                for (int kh = 0; kh < 2; ++kh) {
                    float4 v = xs4[base4 + kd * 42 + kh * 6];
                    const float wk0 = w1[kd * 4 + kh * 2];
                    const float wk1 = w1[kd * 4 + kh * 2 + 1];
                    acc0 += v.x * wk0 + v.y * wk1;
                    acc1 += v.z * wk0 + v.w * wk1;
                }
            h1_sh[d * 72 + h * 12 + 2 * j]     = sigmoidf(acc0);
            h1_sh[d * 72 + h * 12 + 2 * j + 1] = sigmoidf(acc1);
        }
    }
    __syncthreads();

    // ---- Stage 2: conv2 (4,1,2)/s(4,1,2) + sigmoid -> (6,6,6) ----
    if (tid < 216) {
        const int d = tid / 36;
        const int r = tid % 36;
        const int h = r / 6;
        const int w = r % 6;
        float acc = b2[0];
        #pragma unroll
        for (int kd = 0; kd < 4; ++kd)
            #pragma unroll
            for (int kw = 0; kw < 2; ++kw)
                acc += h1_sh[(4 * d + kd) * 72 + h * 12 + (2 * w + kw)] * w2[kd * 2 + kw];
        h2_sh[tid] = sigmoidf(acc);
    }
    __syncthreads();

    // ---- Stage 3: avgpool k=2 -> 27 ----
    if (tid < 27) {
        const int d = tid / 9;
        const int r = tid % 9;
        const int h = r / 3;
        const int w = r % 3;
        float s = 0.f;
        #pragma unroll
        for (int dd = 0; dd < 2; ++dd)
            #pragma unroll
            for (int hh = 0; hh < 2; ++hh)
                #pragma unroll
                for (int ww = 0; ww < 2; ++ww)
                    s += h2_sh[(2 * d + dd) * 36 + (2 * h + hh) * 6 + (2 * w + ww)];
        pool_sh[tid] = s * 0.125f;
    }
    __syncthreads();

    // ---- Stage 4: fc1 27 -> 80 ----
    if (tid < 80) {
        const float* wr = w4 + tid * 27;
        float acc = b4[tid];
        #pragma unroll
        for (int i = 0; i < 27; ++i) acc += pool_sh[i] * wr[i];
        f1_sh[tid] = sigmoidf(acc);
    }
    __syncthreads();

    // ---- Stage 5: fc2 80 -> 200 ----
    if (tid < 200) {
        const float4* wr = (const float4*)(w5 + tid * 80);
        const float4* fv = (const float4*)f1_sh;
        float acc = b5[tid];
        #pragma unroll
        for (int i = 0; i < 20; ++i) {
            float4 a = wr[i], c = fv[i];
            acc += a.x * c.x + a.y * c.y + a.z * c.z + a.w * c.w;
        }
        f2_sh[tid] = sigmoidf(acc);
    }
    __syncthreads();

    // ---- Stage 6: fc3, ONLY rows [i0*52, i0*52+52) ----
    if (tid < 52) {
        const int row = i0 * 52 + tid;
        const float4* wr = (const float4*)(w6 + row * 200);
        const float4* fv = (const float4*)f2_sh;
        float acc = b6[row];
        #pragma unroll 10
        for (int i = 0; i < 50; ++i) {
            float4 a = wr[i], c = fv[i];
            acc += a.x * c.x + a.y * c.y + a.z * c.z + a.w * c.w;
        }
        f3_sh[tid] = sigmoidf(acc);
    }
    __syncthreads();

    // ---- Stage 7: out[b, i0*168 + w] = sum_s f3row[s] * weeks[s][w] ----
    // weeks[s][w] == xs_sh[s*168 + w]; float4 over w (168 = 42 float4).
    if (tid < 42) {
        const float4* xs4 = (const float4*)xs_sh;
        float4 acc = make_float4(0.f, 0.f, 0.f, 0.f);
        #pragma unroll 13
        for (int s = 0; s < 52; ++s) {
            const float fs = f3_sh[s];                 // broadcast
            float4 v = xs4[s * 42 + tid];
            acc.x += fs * v.x;
            acc.y += fs * v.y;
            acc.z += fs * v.z;
            acc.w += fs * v.w;
        }
        float4* ob = (float4*)(out + (size_t)b * 2184 + i0 * 168);
        ob[tid] = acc;
    }
}

extern "C" void kernel_launch(void* const* d_in, const int* in_sizes, int n_in,
                              void* d_out, int out_size, void* d_ws, size_t ws_size,
                              hipStream_t stream) {
    const float* x  = (const float*)d_in[0];
    const float* w1 = (const float*)d_in[1];
    const float* b1 = (const float*)d_in[2];
    const float* w2 = (const float*)d_in[3];
    const float* b2 = (const float*)d_in[4];
    const float* w4 = (const float*)d_in[5];
    const float* b4 = (const float*)d_in[6];
    const float* w5 = (const float*)d_in[7];
    const float* b5 = (const float*)d_in[8];
    const float* w6 = (const float*)d_in[9];
    const float* b6 = (const float*)d_in[10];
    float* out = (float*)d_out;

    dim3 grid(13, 10);
    c3dnet_fused<<<grid, 256, 0, stream>>>(x, w1, b1, w2, b2, w4, b4,
                                           w5, b5, w6, b6, out);
}